// Round 2
// baseline (486.388 us; speedup 1.0000x reference)
//
#include <hip/hip_runtime.h>
#include <math.h>

#define NH 4
#define NF 64
#define NM 32

__device__ __forceinline__ float softplusf(float v){ return fmaxf(v, 0.f) + log1pf(expf(-fabsf(v))); }
__device__ __forceinline__ float sigmoidf_(float v){ return 1.f / (1.f + expf(-v)); }
// order-preserving float->uint key for atomicMax
__device__ __forceinline__ unsigned fkey(float f){ unsigned u = __float_as_uint(f); return u ^ ((u >> 31) ? 0xffffffffu : 0x80000000u); }
__device__ __forceinline__ float funkey(unsigned k){ return __uint_as_float(k ^ ((k >> 31) ? 0x80000000u : 0xffffffffu)); }

#define NEG_KEY 0x007FFFFFu  // fkey(-inf)

// ---------------- K0: init accumulators ----------------
__global__ void k_init(float* __restrict__ S, float* __restrict__ C1, float* __restrict__ C2,
                       float* __restrict__ rsum, float* __restrict__ tsum,
                       unsigned* __restrict__ rmax, unsigned* __restrict__ tmax, int N) {
  int i = blockIdx.x * blockDim.x + threadIdx.x;
  if (i < N * NF) S[i] = 0.f;
  if (i < NH * N) {
    C1[i] = 0.f; C2[i] = 0.f; rsum[i] = 0.f; tsum[i] = 0.f;
    rmax[i] = NEG_KEY; tmax[i] = NEG_KEY;
  }
}

// ---------------- K1: per-node projections + scalars ----------------
// block = 256 threads = 4 waves; wave h handles head h of node blockIdx.x
__global__ void k_node(const float* __restrict__ x,
                       const float* __restrict__ Wp, const float* __restrict__ Wr, const float* __restrict__ Wt,
                       const float* __restrict__ rsc, const float* __restrict__ tsc,
                       const float* __restrict__ dW1, const float* __restrict__ db1,
                       const float* __restrict__ dw2, const float* __restrict__ db2,
                       const float* __restrict__ tW1, const float* __restrict__ tb1,
                       const float* __restrict__ tw2, const float* __restrict__ tb2,
                       float* __restrict__ rp, float* __restrict__ tp,
                       float* __restrict__ sr, float* __restrict__ st,
                       float* __restrict__ doff, float* __restrict__ toff, int N) {
  int n = blockIdx.x;
  int tid = threadIdx.x;
  int h = tid >> 6;
  int g = tid & 63;
  __shared__ float xs[NF];
  __shared__ float eps[NH][NF];
  if (tid < NF) xs[tid] = x[n * NF + tid];
  __syncthreads();

  const float* Wph = Wp + h * NF * NF;
  const float* Wrh = Wr + h * NF * NF;
  const float* Wth = Wt + h * NF * NF;
  float ep = 0.f, rpv = 0.f, tpv = 0.f;
  #pragma unroll 8
  for (int f = 0; f < NF; ++f) {
    float xv = xs[f];
    ep  += xv * Wph[f * NF + g];
    rpv += xv * Wrh[f * NF + g];
    tpv += xv * Wth[f * NF + g];
  }
  rp[((size_t)h * N + n) * NF + g] = rpv;
  tp[((size_t)h * N + n) * NF + g] = tpv;
  eps[h][g] = ep;

  float a = ep * rsc[h * NF + g];
  float b = ep * tsc[h * NF + g];
  for (int off = 32; off; off >>= 1) { a += __shfl_xor(a, off); b += __shfl_xor(b, off); }
  if (g == 0) { sr[h * N + n] = a; st[h * N + n] = b; }
  __syncthreads();

  // MLPs: lanes 0..31 -> decay, lanes 32..63 -> temp (same head)
  int m = g & 31;
  bool isTemp = (g >= 32);
  const float* W1 = isTemp ? tW1 : dW1;
  const float* b1 = isTemp ? tb1 : db1;
  float acc = b1[h * NM + m];
  #pragma unroll 8
  for (int f = 0; f < NF; ++f) acc += eps[h][f] * W1[(h * NF + f) * NM + m];
  float h1 = acc * sigmoidf_(acc);  // silu
  float w2v = isTemp ? tw2[h * NM + m] : dw2[h * NM + m];
  float p = h1 * w2v;
  for (int off = 16; off; off >>= 1) p += __shfl_xor(p, off);
  if (m == 0) {
    if (!isTemp) doff[h * N + n] = p + db2[h];
    else         toff[h * N + n] = p + tb2[h];
  }
}

// ---------------- K2: per edge-head logits + segment max ----------------
__global__ void k_logits(const int* __restrict__ ei, const float* __restrict__ elen,
                         const float* __restrict__ sr, const float* __restrict__ st,
                         const float* __restrict__ doff, const float* __restrict__ toff,
                         const float* __restrict__ rdls, const float* __restrict__ rtb, const float* __restrict__ rtw,
                         float* __restrict__ rl, float* __restrict__ tl,
                         unsigned* __restrict__ rmax, unsigned* __restrict__ tmax, int E, int N) {
  int e = blockIdx.x * blockDim.x + threadIdx.x;
  int h = blockIdx.y;
  if (e >= E) return;
  int s = ei[e], r = ei[E + e];
  float len = elen[e];
  float rdscale = softplusf(rdls[h]);
  float logit = sr[h * N + s] - sr[h * N + r] - (rdscale + doff[h * N + r]) * len;
  float temp = softplusf(rtb[h] + rtw[h] * len + toff[h * N + r]);
  float rlv = logit / (temp + 1e-4f);
  float tlv = st[h * N + s] - st[h * N + r];
  rl[(size_t)h * E + e] = rlv;
  tl[(size_t)h * E + e] = tlv;
  atomicMax(&rmax[h * N + r], fkey(rlv));
  atomicMax(&tmax[h * N + r], fkey(tlv));
}

// ---------------- K3: exp + segment sum ----------------
__global__ void k_expsum(const int* __restrict__ ei,
                         float* __restrict__ rl, float* __restrict__ tl,
                         const unsigned* __restrict__ rmax, const unsigned* __restrict__ tmax,
                         float* __restrict__ rsum, float* __restrict__ tsum, int E, int N) {
  int e = blockIdx.x * blockDim.x + threadIdx.x;
  int h = blockIdx.y;
  if (e >= E) return;
  int r = ei[E + e];
  float mr = funkey(rmax[h * N + r]);
  float mt = funkey(tmax[h * N + r]);
  float er_ = expf(rl[(size_t)h * E + e] - mr);
  float et_ = expf(tl[(size_t)h * E + e] - mt);
  rl[(size_t)h * E + e] = er_;
  tl[(size_t)h * E + e] = et_;
  atomicAdd(&rsum[h * N + r], er_);
  atomicAdd(&tsum[h * N + r], et_);
}

// ---------------- K4: weighted scatter (wave per edge, lane = feature) ----------------
__global__ void k_agg(const int* __restrict__ ei, const float* __restrict__ elen,
                      const float* __restrict__ rexp, const float* __restrict__ texp,
                      const float* __restrict__ rsum, const float* __restrict__ tsum,
                      const float* __restrict__ mixb, const float* __restrict__ mixs,
                      const float* __restrict__ rp, const float* __restrict__ tp,
                      float* __restrict__ S, float* __restrict__ C1, float* __restrict__ C2, int E, int N) {
  int wid = (int)((blockIdx.x * (size_t)blockDim.x + threadIdx.x) >> 6);
  int lane = threadIdx.x & 63;
  if (wid >= E) return;
  int s = ei[wid], r = ei[E + wid];
  float len = elen[wid];
  float c1[NH], c2[NH];
  float val = 0.f;
  #pragma unroll
  for (int h = 0; h < NH; ++h) {
    float ar = rexp[(size_t)h * E + wid] / (rsum[h * N + r] + 1e-9f);
    float at = texp[(size_t)h * E + wid] / (tsum[h * N + r] + 1e-9f);
    float g = sigmoidf_(mixb[h] + mixs[h] * len);
    float ba = g * ar + (1.f - g) * at;
    c1[h] = ba * g;
    c2[h] = ba * (1.f - g);
    val += c1[h] * rp[((size_t)h * N + s) * NF + lane] + c2[h] * tp[((size_t)h * N + s) * NF + lane];
  }
  atomicAdd(&S[(size_t)r * NF + lane], val);
  if (lane < NH)               atomicAdd(&C1[lane * N + r], c1[lane]);
  else if (lane < 2 * NH)      atomicAdd(&C2[(lane - NH) * N + r], c2[lane - NH]);
}

// ---------------- K5: correction + @Wout + residual ----------------
__global__ void k_out(const float* __restrict__ x, const float* __restrict__ S,
                      const float* __restrict__ C1, const float* __restrict__ C2,
                      const float* __restrict__ rp, const float* __restrict__ tp,
                      const float* __restrict__ Wout, float* __restrict__ out, int N) {
  __shared__ float am_s[4][NF];
  __shared__ float wout_s[NF * NF];
  int tid = threadIdx.x;
  for (int i = tid; i < NF * NF; i += 256) wout_s[i] = Wout[i];
  int w = tid >> 6, lane = tid & 63;
  int n = blockIdx.x * 4 + w;
  float am = 0.f;
  if (n < N) {
    am = S[(size_t)n * NF + lane];
    #pragma unroll
    for (int h = 0; h < NH; ++h) {
      am -= C1[h * N + n] * rp[((size_t)h * N + n) * NF + lane]
          + C2[h * N + n] * tp[((size_t)h * N + n) * NF + lane];
    }
    am *= (1.f / NH);
  }
  am_s[w][lane] = am;
  __syncthreads();
  if (n < N) {
    float acc = x[(size_t)n * NF + lane];
    #pragma unroll 8
    for (int f = 0; f < NF; ++f) acc += am_s[w][f] * wout_s[f * NF + lane];
    out[(size_t)n * NF + lane] = acc;
  }
}

extern "C" void kernel_launch(void* const* d_in, const int* in_sizes, int n_in,
                              void* d_out, int out_size, void* d_ws, size_t ws_size,
                              hipStream_t stream) {
  const float* x    = (const float*)d_in[0];
  const int*   ei   = (const int*)d_in[1];
  // d_in[2] = edge_vec, unused by the reference
  const float* elen = (const float*)d_in[3];
  const float* Wp   = (const float*)d_in[4];
  const float* Wr   = (const float*)d_in[5];
  const float* Wt   = (const float*)d_in[6];
  const float* rsc  = (const float*)d_in[7];
  const float* tsc  = (const float*)d_in[8];
  const float* rdls = (const float*)d_in[9];
  const float* rtb  = (const float*)d_in[10];
  const float* rtw  = (const float*)d_in[11];
  const float* mixb = (const float*)d_in[12];
  const float* mixs = (const float*)d_in[13];
  const float* dW1  = (const float*)d_in[14];
  const float* db1  = (const float*)d_in[15];
  const float* dw2  = (const float*)d_in[16];
  const float* db2  = (const float*)d_in[17];
  const float* tW1  = (const float*)d_in[18];
  const float* tb1  = (const float*)d_in[19];
  const float* tw2  = (const float*)d_in[20];
  const float* tb2  = (const float*)d_in[21];
  const float* Wout = (const float*)d_in[22];

  int N = in_sizes[0] / NF;
  int E = in_sizes[3];

  float* p = (float*)d_ws;
  float* rp   = p; p += (size_t)NH * N * NF;
  float* tp   = p; p += (size_t)NH * N * NF;
  float* sr   = p; p += (size_t)NH * N;
  float* st   = p; p += (size_t)NH * N;
  float* doff = p; p += (size_t)NH * N;
  float* toff = p; p += (size_t)NH * N;
  float* rl   = p; p += (size_t)NH * E;
  float* tl   = p; p += (size_t)NH * E;
  float* rsum = p; p += (size_t)NH * N;
  float* tsum = p; p += (size_t)NH * N;
  float* C1   = p; p += (size_t)NH * N;
  float* C2   = p; p += (size_t)NH * N;
  unsigned* rmax = (unsigned*)p; p += (size_t)NH * N;
  unsigned* tmax = (unsigned*)p; p += (size_t)NH * N;
  float* S    = p; p += (size_t)N * NF;

  // K0: init accumulators
  {
    int total = N * NF;
    k_init<<<(total + 255) / 256, 256, 0, stream>>>(S, C1, C2, rsum, tsum, rmax, tmax, N);
  }
  // K1: node pass
  k_node<<<N, 256, 0, stream>>>(x, Wp, Wr, Wt, rsc, tsc, dW1, db1, dw2, db2,
                                tW1, tb1, tw2, tb2, rp, tp, sr, st, doff, toff, N);
  // K2: logits + segment max
  {
    dim3 grid((E + 255) / 256, NH);
    k_logits<<<grid, 256, 0, stream>>>(ei, elen, sr, st, doff, toff, rdls, rtb, rtw,
                                       rl, tl, rmax, tmax, E, N);
  }
  // K3: exp + segment sum
  {
    dim3 grid((E + 255) / 256, NH);
    k_expsum<<<grid, 256, 0, stream>>>(ei, rl, tl, rmax, tmax, rsum, tsum, E, N);
  }
  // K4: weighted scatter
  {
    size_t waves = (size_t)E;
    size_t blocks = (waves * 64 + 255) / 256;
    k_agg<<<(int)blocks, 256, 0, stream>>>(ei, elen, rl, tl, rsum, tsum, mixb, mixs,
                                           rp, tp, S, C1, C2, E, N);
  }
  // K5: output
  k_out<<<(N + 3) / 4, 256, 0, stream>>>(x, S, C1, C2, rp, tp, Wout, (float*)d_out, N);
}

// Round 3
// 386.331 us; speedup vs baseline: 1.2590x; 1.2590x over previous
//
#include <hip/hip_runtime.h>
#include <math.h>

#define NH 4
#define NF 64
#define NM 32
#define NT 16  // nodes per block in k_proj

__device__ __forceinline__ float softplusf(float v){ return fmaxf(v, 0.f) + log1pf(expf(-fabsf(v))); }
__device__ __forceinline__ float sigmoidf_(float v){ return 1.f / (1.f + expf(-v)); }
// order-preserving float->uint key for atomicMax
__device__ __forceinline__ unsigned fkey(float f){ unsigned u = __float_as_uint(f); return u ^ ((u >> 31) ? 0xffffffffu : 0x80000000u); }
__device__ __forceinline__ float funkey(unsigned k){ return __uint_as_float(k ^ ((k >> 31) ? 0x80000000u : 0xffffffffu)); }

#define NEG_KEY 0x007FFFFFu  // fkey(-inf)

// ---------------- K0: init accumulators ----------------
__global__ void k_init(float* __restrict__ S, float* __restrict__ C1, float* __restrict__ C2,
                       float* __restrict__ rsum, float* __restrict__ tsum,
                       unsigned* __restrict__ rmax, unsigned* __restrict__ tmax, int N) {
  int i = blockIdx.x * blockDim.x + threadIdx.x;
  if (i < N * NF) S[i] = 0.f;
  if (i < NH * N) {
    C1[i] = 0.f; C2[i] = 0.f; rsum[i] = 0.f; tsum[i] = 0.f;
    rmax[i] = NEG_KEY; tmax[i] = NEG_KEY;
  }
}

// ---------------- K1: tiled node pass ----------------
// grid = (ceil(N/NT), 3); block = 256 = 4 heads x 64 cols.
// mat 0: ep (kept in LDS) + sr/st + decay/temp MLPs. mat 1: rp. mat 2: tp.
// Weight loads amortized over NT nodes (16 FMA per L2 load).
__global__ void k_proj(const float* __restrict__ x,
                       const float* __restrict__ Wp, const float* __restrict__ Wr, const float* __restrict__ Wt,
                       const float* __restrict__ rsc, const float* __restrict__ tsc,
                       const float* __restrict__ dW1, const float* __restrict__ db1,
                       const float* __restrict__ dw2, const float* __restrict__ db2,
                       const float* __restrict__ tW1, const float* __restrict__ tb1,
                       const float* __restrict__ tw2, const float* __restrict__ tb2,
                       float* __restrict__ rp, float* __restrict__ tp,
                       float* __restrict__ sr, float* __restrict__ st,
                       float* __restrict__ doff, float* __restrict__ toff, int N) {
  int n0 = blockIdx.x * NT;
  int mat = blockIdx.y;
  int tid = threadIdx.x;
  int h = tid >> 6, g = tid & 63;
  __shared__ float xs[NT][NF];
  __shared__ float eps[NT][NH][NF];

  for (int i = tid; i < NT * NF; i += 256) {
    int n = i >> 6, f = i & 63;
    xs[n][f] = (n0 + n < N) ? x[(size_t)(n0 + n) * NF + f] : 0.f;
  }
  __syncthreads();

  const float* W = (mat == 0 ? Wp : (mat == 1 ? Wr : Wt)) + (size_t)h * NF * NF;
  float acc[NT];
  #pragma unroll
  for (int n = 0; n < NT; ++n) acc[n] = 0.f;
  #pragma unroll 4
  for (int f = 0; f < NF; ++f) {
    float wv = W[f * NF + g];
    #pragma unroll
    for (int n = 0; n < NT; ++n) acc[n] += xs[n][f] * wv;
  }

  if (mat != 0) {
    float* dst = (mat == 1) ? rp : tp;
    #pragma unroll
    for (int n = 0; n < NT; ++n)
      if (n0 + n < N) dst[((size_t)h * N + n0 + n) * NF + g] = acc[n];
    return;
  }

  // mat == 0: ep path
  #pragma unroll
  for (int n = 0; n < NT; ++n) eps[n][h][g] = acc[n];

  float rs = rsc[h * NF + g], ts = tsc[h * NF + g];
  for (int n = 0; n < NT; ++n) {
    float a = acc[n] * rs, b = acc[n] * ts;
    for (int off = 32; off; off >>= 1) { a += __shfl_xor(a, off); b += __shfl_xor(b, off); }
    if (g == 0 && n0 + n < N) { sr[h * N + n0 + n] = a; st[h * N + n0 + n] = b; }
  }
  __syncthreads();

  // MLPs: lanes 0..31 decay, 32..63 temp; one m per lane, weights reused over NT nodes
  int m = g & 31;
  bool isTemp = (g >= 32);
  const float* W1 = isTemp ? tW1 : dW1;
  float bias = isTemp ? tb1[h * NM + m] : db1[h * NM + m];
  float w2v  = isTemp ? tw2[h * NM + m] : dw2[h * NM + m];
  float accm[NT];
  #pragma unroll
  for (int n = 0; n < NT; ++n) accm[n] = bias;
  #pragma unroll 4
  for (int f = 0; f < NF; ++f) {
    float wv = W1[(h * NF + f) * NM + m];
    #pragma unroll
    for (int n = 0; n < NT; ++n) accm[n] += eps[n][h][f] * wv;
  }
  for (int n = 0; n < NT; ++n) {
    float a = accm[n];
    float p = a * sigmoidf_(a) * w2v;  // silu * w2
    for (int off = 16; off; off >>= 1) p += __shfl_xor(p, off);
    if (m == 0 && n0 + n < N) {
      if (!isTemp) doff[h * N + n0 + n] = p + db2[h];
      else         toff[h * N + n0 + n] = p + tb2[h];
    }
  }
}

// ---------------- K2: per-edge logits (all heads) + segment max ----------------
__global__ void k_logits(const int* __restrict__ ei, const float* __restrict__ elen,
                         const float* __restrict__ sr, const float* __restrict__ st,
                         const float* __restrict__ doff, const float* __restrict__ toff,
                         const float* __restrict__ rdls, const float* __restrict__ rtb, const float* __restrict__ rtw,
                         float* __restrict__ rl, float* __restrict__ tl,
                         unsigned* __restrict__ rmax, unsigned* __restrict__ tmax, int E, int N) {
  int e = blockIdx.x * blockDim.x + threadIdx.x;
  if (e >= E) return;
  int s = ei[e], r = ei[E + e];
  float len = elen[e];
  #pragma unroll
  for (int h = 0; h < NH; ++h) {
    float rdscale = softplusf(rdls[h]);
    float logit = sr[h * N + s] - sr[h * N + r] - (rdscale + doff[h * N + r]) * len;
    float temp = softplusf(rtb[h] + rtw[h] * len + toff[h * N + r]);
    float rlv = logit / (temp + 1e-4f);
    float tlv = st[h * N + s] - st[h * N + r];
    rl[(size_t)h * E + e] = rlv;
    tl[(size_t)h * E + e] = tlv;
    atomicMax(&rmax[h * N + r], fkey(rlv));
    atomicMax(&tmax[h * N + r], fkey(tlv));
  }
}

// ---------------- K3: exp + segment sum (all heads) ----------------
__global__ void k_expsum(const int* __restrict__ ei,
                         float* __restrict__ rl, float* __restrict__ tl,
                         const unsigned* __restrict__ rmax, const unsigned* __restrict__ tmax,
                         float* __restrict__ rsum, float* __restrict__ tsum, int E, int N) {
  int e = blockIdx.x * blockDim.x + threadIdx.x;
  if (e >= E) return;
  int r = ei[E + e];
  #pragma unroll
  for (int h = 0; h < NH; ++h) {
    float mr = funkey(rmax[h * N + r]);
    float mt = funkey(tmax[h * N + r]);
    float er_ = expf(rl[(size_t)h * E + e] - mr);
    float et_ = expf(tl[(size_t)h * E + e] - mt);
    rl[(size_t)h * E + e] = er_;
    tl[(size_t)h * E + e] = et_;
    atomicAdd(&rsum[h * N + r], er_);
    atomicAdd(&tsum[h * N + r], et_);
  }
}

// ---------------- K4: weighted scatter (wave per edge, lane = feature) ----------------
__global__ void k_agg(const int* __restrict__ ei, const float* __restrict__ elen,
                      const float* __restrict__ rexp, const float* __restrict__ texp,
                      const float* __restrict__ rsum, const float* __restrict__ tsum,
                      const float* __restrict__ mixb, const float* __restrict__ mixs,
                      const float* __restrict__ rp, const float* __restrict__ tp,
                      float* __restrict__ S, float* __restrict__ C1, float* __restrict__ C2, int E, int N) {
  int wid = (int)((blockIdx.x * (size_t)blockDim.x + threadIdx.x) >> 6);
  int lane = threadIdx.x & 63;
  if (wid >= E) return;
  int s = ei[wid], r = ei[E + wid];
  float len = elen[wid];
  float c1[NH], c2[NH];
  float val = 0.f;
  #pragma unroll
  for (int h = 0; h < NH; ++h) {
    float ar = rexp[(size_t)h * E + wid] / (rsum[h * N + r] + 1e-9f);
    float at = texp[(size_t)h * E + wid] / (tsum[h * N + r] + 1e-9f);
    float g = sigmoidf_(mixb[h] + mixs[h] * len);
    float ba = g * ar + (1.f - g) * at;
    c1[h] = ba * g;
    c2[h] = ba * (1.f - g);
    val += c1[h] * rp[((size_t)h * N + s) * NF + lane] + c2[h] * tp[((size_t)h * N + s) * NF + lane];
  }
  atomicAdd(&S[(size_t)r * NF + lane], val);
  if (lane < NH)               atomicAdd(&C1[lane * N + r], c1[lane]);
  else if (lane < 2 * NH)      atomicAdd(&C2[(lane - NH) * N + r], c2[lane - NH]);
}

// ---------------- K5: correction + @Wout + residual ----------------
__global__ void k_out(const float* __restrict__ x, const float* __restrict__ S,
                      const float* __restrict__ C1, const float* __restrict__ C2,
                      const float* __restrict__ rp, const float* __restrict__ tp,
                      const float* __restrict__ Wout, float* __restrict__ out, int N) {
  __shared__ float am_s[4][NF];
  __shared__ float wout_s[NF * NF];
  int tid = threadIdx.x;
  for (int i = tid; i < NF * NF; i += 256) wout_s[i] = Wout[i];
  int w = tid >> 6, lane = tid & 63;
  int n = blockIdx.x * 4 + w;
  float am = 0.f;
  if (n < N) {
    am = S[(size_t)n * NF + lane];
    #pragma unroll
    for (int h = 0; h < NH; ++h) {
      am -= C1[h * N + n] * rp[((size_t)h * N + n) * NF + lane]
          + C2[h * N + n] * tp[((size_t)h * N + n) * NF + lane];
    }
    am *= (1.f / NH);
  }
  am_s[w][lane] = am;
  __syncthreads();
  if (n < N) {
    float acc = x[(size_t)n * NF + lane];
    #pragma unroll 8
    for (int f = 0; f < NF; ++f) acc += am_s[w][f] * wout_s[f * NF + lane];
    out[(size_t)n * NF + lane] = acc;
  }
}

extern "C" void kernel_launch(void* const* d_in, const int* in_sizes, int n_in,
                              void* d_out, int out_size, void* d_ws, size_t ws_size,
                              hipStream_t stream) {
  const float* x    = (const float*)d_in[0];
  const int*   ei   = (const int*)d_in[1];
  // d_in[2] = edge_vec, unused by the reference
  const float* elen = (const float*)d_in[3];
  const float* Wp   = (const float*)d_in[4];
  const float* Wr   = (const float*)d_in[5];
  const float* Wt   = (const float*)d_in[6];
  const float* rsc  = (const float*)d_in[7];
  const float* tsc  = (const float*)d_in[8];
  const float* rdls = (const float*)d_in[9];
  const float* rtb  = (const float*)d_in[10];
  const float* rtw  = (const float*)d_in[11];
  const float* mixb = (const float*)d_in[12];
  const float* mixs = (const float*)d_in[13];
  const float* dW1  = (const float*)d_in[14];
  const float* db1  = (const float*)d_in[15];
  const float* dw2  = (const float*)d_in[16];
  const float* db2  = (const float*)d_in[17];
  const float* tW1  = (const float*)d_in[18];
  const float* tb1  = (const float*)d_in[19];
  const float* tw2  = (const float*)d_in[20];
  const float* tb2  = (const float*)d_in[21];
  const float* Wout = (const float*)d_in[22];

  int N = in_sizes[0] / NF;
  int E = in_sizes[3];

  float* p = (float*)d_ws;
  float* rp   = p; p += (size_t)NH * N * NF;
  float* tp   = p; p += (size_t)NH * N * NF;
  float* sr   = p; p += (size_t)NH * N;
  float* st   = p; p += (size_t)NH * N;
  float* doff = p; p += (size_t)NH * N;
  float* toff = p; p += (size_t)NH * N;
  float* rl   = p; p += (size_t)NH * E;
  float* tl   = p; p += (size_t)NH * E;
  float* rsum = p; p += (size_t)NH * N;
  float* tsum = p; p += (size_t)NH * N;
  float* C1   = p; p += (size_t)NH * N;
  float* C2   = p; p += (size_t)NH * N;
  unsigned* rmax = (unsigned*)p; p += (size_t)NH * N;
  unsigned* tmax = (unsigned*)p; p += (size_t)NH * N;
  float* S    = p; p += (size_t)N * NF;

  // K0: init accumulators
  {
    int total = N * NF;
    k_init<<<(total + 255) / 256, 256, 0, stream>>>(S, C1, C2, rsum, tsum, rmax, tmax, N);
  }
  // K1: tiled node pass
  {
    dim3 grid((N + NT - 1) / NT, 3);
    k_proj<<<grid, 256, 0, stream>>>(x, Wp, Wr, Wt, rsc, tsc, dW1, db1, dw2, db2,
                                     tW1, tb1, tw2, tb2, rp, tp, sr, st, doff, toff, N);
  }
  // K2: logits + segment max
  k_logits<<<(E + 255) / 256, 256, 0, stream>>>(ei, elen, sr, st, doff, toff, rdls, rtb, rtw,
                                                rl, tl, rmax, tmax, E, N);
  // K3: exp + segment sum
  k_expsum<<<(E + 255) / 256, 256, 0, stream>>>(ei, rl, tl, rmax, tmax, rsum, tsum, E, N);
  // K4: weighted scatter
  {
    size_t blocks = ((size_t)E * 64 + 255) / 256;
    k_agg<<<(int)blocks, 256, 0, stream>>>(ei, elen, rl, tl, rsum, tsum, mixb, mixs,
                                           rp, tp, S, C1, C2, E, N);
  }
  // K5: output
  k_out<<<(N + 3) / 4, 256, 0, stream>>>(x, S, C1, C2, rp, tp, Wout, (float*)d_out, N);
}

// Round 4
// 370.653 us; speedup vs baseline: 1.3122x; 1.0423x over previous
//
#include <hip/hip_runtime.h>
#include <math.h>

#define NH 4
#define NF 64
#define NM 32
#define NT 16  // nodes per block in k_proj

__device__ __forceinline__ float softplusf(float v){ return fmaxf(v, 0.f) + log1pf(expf(-fabsf(v))); }
__device__ __forceinline__ float sigmoidf_(float v){ return 1.f / (1.f + expf(-v)); }
// order-preserving float->uint key for atomicMax
__device__ __forceinline__ unsigned fkey(float f){ unsigned u = __float_as_uint(f); return u ^ ((u >> 31) ? 0xffffffffu : 0x80000000u); }
__device__ __forceinline__ float funkey(unsigned k){ return __uint_as_float(k ^ ((k >> 31) ? 0x80000000u : 0xffffffffu)); }

#define NEG_KEY 0x007FFFFFu  // fkey(-inf)

// ---------------- K0: init accumulators ----------------
__global__ void k_init(float* __restrict__ rsum, float* __restrict__ tsum,
                       unsigned* __restrict__ rmax, unsigned* __restrict__ tmax,
                       int* __restrict__ deg, int* __restrict__ cursor, int N) {
  int i = blockIdx.x * blockDim.x + threadIdx.x;
  if (i < NH * N) {
    rsum[i] = 0.f; tsum[i] = 0.f;
    rmax[i] = NEG_KEY; tmax[i] = NEG_KEY;
  }
  if (i < N) { deg[i] = 0; cursor[i] = 0; }
}

// ---------------- K1: tiled node pass ----------------
// grid = (ceil(N/NT), 3); block = 256 = 4 heads x 64 cols.
// mat 0: ep (kept in LDS) + sr/st + decay/temp MLPs. mat 1: rp half of pt. mat 2: tp half.
// pt layout: [n][8][64], rows 0..3 = rp heads, 4..7 = tp heads (2KB blob per node).
// per-node head scalars sr/st/doff/toff laid out [n][4] for float4 edge loads.
__global__ void k_proj(const float* __restrict__ x,
                       const float* __restrict__ Wp, const float* __restrict__ Wr, const float* __restrict__ Wt,
                       const float* __restrict__ rsc, const float* __restrict__ tsc,
                       const float* __restrict__ dW1, const float* __restrict__ db1,
                       const float* __restrict__ dw2, const float* __restrict__ db2,
                       const float* __restrict__ tW1, const float* __restrict__ tb1,
                       const float* __restrict__ tw2, const float* __restrict__ tb2,
                       float* __restrict__ pt,
                       float* __restrict__ sr, float* __restrict__ st,
                       float* __restrict__ doff, float* __restrict__ toff, int N) {
  int n0 = blockIdx.x * NT;
  int mat = blockIdx.y;
  int tid = threadIdx.x;
  int h = tid >> 6, g = tid & 63;
  __shared__ float xs[NT][NF];
  __shared__ float eps[NT][NH][NF];

  for (int i = tid; i < NT * NF; i += 256) {
    int n = i >> 6, f = i & 63;
    xs[n][f] = (n0 + n < N) ? x[(size_t)(n0 + n) * NF + f] : 0.f;
  }
  __syncthreads();

  const float* W = (mat == 0 ? Wp : (mat == 1 ? Wr : Wt)) + (size_t)h * NF * NF;
  float acc[NT];
  #pragma unroll
  for (int n = 0; n < NT; ++n) acc[n] = 0.f;
  #pragma unroll 4
  for (int f = 0; f < NF; ++f) {
    float wv = W[f * NF + g];
    #pragma unroll
    for (int n = 0; n < NT; ++n) acc[n] += xs[n][f] * wv;
  }

  if (mat != 0) {
    int row = (mat - 1) * NH + h;  // 0..7
    #pragma unroll
    for (int n = 0; n < NT; ++n)
      if (n0 + n < N) pt[((size_t)(n0 + n) * 2 * NH + row) * NF + g] = acc[n];
    return;
  }

  // mat == 0: ep path
  #pragma unroll
  for (int n = 0; n < NT; ++n) eps[n][h][g] = acc[n];

  float rs = rsc[h * NF + g], ts = tsc[h * NF + g];
  for (int n = 0; n < NT; ++n) {
    float a = acc[n] * rs, b = acc[n] * ts;
    for (int off = 32; off; off >>= 1) { a += __shfl_xor(a, off); b += __shfl_xor(b, off); }
    if (g == 0 && n0 + n < N) { sr[(n0 + n) * NH + h] = a; st[(n0 + n) * NH + h] = b; }
  }
  __syncthreads();

  // MLPs: lanes 0..31 decay, 32..63 temp; one m per lane, weights reused over NT nodes
  int m = g & 31;
  bool isTemp = (g >= 32);
  const float* W1 = isTemp ? tW1 : dW1;
  float bias = isTemp ? tb1[h * NM + m] : db1[h * NM + m];
  float w2v  = isTemp ? tw2[h * NM + m] : dw2[h * NM + m];
  float accm[NT];
  #pragma unroll
  for (int n = 0; n < NT; ++n) accm[n] = bias;
  #pragma unroll 4
  for (int f = 0; f < NF; ++f) {
    float wv = W1[(h * NF + f) * NM + m];
    #pragma unroll
    for (int n = 0; n < NT; ++n) accm[n] += eps[n][h][f] * wv;
  }
  for (int n = 0; n < NT; ++n) {
    float a = accm[n];
    float p = a * sigmoidf_(a) * w2v;  // silu * w2
    for (int off = 16; off; off >>= 1) p += __shfl_xor(p, off);
    if (m == 0 && n0 + n < N) {
      if (!isTemp) doff[(n0 + n) * NH + h] = p + db2[h];
      else         toff[(n0 + n) * NH + h] = p + tb2[h];
    }
  }
}

// ---------------- K2: per-edge logits (all heads) + segment max + degree count ----------------
__global__ void k_logits(const int* __restrict__ ei, const float* __restrict__ elen,
                         const float4* __restrict__ sr4, const float4* __restrict__ st4,
                         const float4* __restrict__ doff4, const float4* __restrict__ toff4,
                         const float* __restrict__ rdls, const float* __restrict__ rtb, const float* __restrict__ rtw,
                         float4* __restrict__ rl4, float4* __restrict__ tl4,
                         unsigned* __restrict__ rmax, unsigned* __restrict__ tmax,
                         int* __restrict__ deg, int E, int N) {
  int e = blockIdx.x * blockDim.x + threadIdx.x;
  if (e >= E) return;
  int s = ei[e], r = ei[E + e];
  float len = elen[e];
  atomicAdd(&deg[r], 1);
  float4 a = sr4[s], b = sr4[r], c = st4[s], d = st4[r], dof = doff4[r], tof = toff4[r];
  const float* ap = (const float*)&a; const float* bp = (const float*)&b;
  const float* cp = (const float*)&c; const float* dp = (const float*)&d;
  const float* dofp = (const float*)&dof; const float* tofp = (const float*)&tof;
  float rlv[NH], tlv[NH];
  #pragma unroll
  for (int h = 0; h < NH; ++h) {
    float rdscale = softplusf(rdls[h]);
    float logit = ap[h] - bp[h] - (rdscale + dofp[h]) * len;
    float temp = softplusf(rtb[h] + rtw[h] * len + tofp[h]);
    rlv[h] = logit / (temp + 1e-4f);
    tlv[h] = cp[h] - dp[h];
    atomicMax(&rmax[r * NH + h], fkey(rlv[h]));
    atomicMax(&tmax[r * NH + h], fkey(tlv[h]));
  }
  rl4[e] = make_float4(rlv[0], rlv[1], rlv[2], rlv[3]);
  tl4[e] = make_float4(tlv[0], tlv[1], tlv[2], tlv[3]);
}

// ---------------- K2b: exclusive prefix scan of degrees (single block) ----------------
__global__ void k_scan(const int* __restrict__ deg, int* __restrict__ start, int N) {
  __shared__ int sd[1024];
  __shared__ int sbase;
  int tid = threadIdx.x;
  if (tid == 0) sbase = 0;
  __syncthreads();
  int nc = (N + 1023) >> 10;
  for (int c = 0; c < nc; ++c) {
    int i = (c << 10) + tid;
    int v = (i < N) ? deg[i] : 0;
    sd[tid] = v;
    __syncthreads();
    for (int off = 1; off < 1024; off <<= 1) {
      int t = (tid >= off) ? sd[tid - off] : 0;
      __syncthreads();
      sd[tid] += t;
      __syncthreads();
    }
    int base = sbase;
    if (i < N) start[i] = base + sd[tid] - v;
    int total = sd[1023];
    __syncthreads();
    if (tid == 0) sbase = base + total;
    __syncthreads();
  }
  if (tid == 0) start[N] = sbase;
}

// ---------------- K3: exp + segment sum (all heads) ----------------
__global__ void k_expsum(const int* __restrict__ ei,
                         float4* __restrict__ rl4, float4* __restrict__ tl4,
                         const uint4* __restrict__ rmax4, const uint4* __restrict__ tmax4,
                         float* __restrict__ rsum, float* __restrict__ tsum, int E, int N) {
  int e = blockIdx.x * blockDim.x + threadIdx.x;
  if (e >= E) return;
  int r = ei[E + e];
  float4 rv = rl4[e], tv = tl4[e];
  uint4 mr = rmax4[r], mt = tmax4[r];
  float* rvp = (float*)&rv; float* tvp = (float*)&tv;
  const unsigned* mrp = (const unsigned*)&mr; const unsigned* mtp = (const unsigned*)&mt;
  #pragma unroll
  for (int h = 0; h < NH; ++h) {
    float er_ = expf(rvp[h] - funkey(mrp[h]));
    float et_ = expf(tvp[h] - funkey(mtp[h]));
    rvp[h] = er_; tvp[h] = et_;
    atomicAdd(&rsum[r * NH + h], er_);
    atomicAdd(&tsum[r * NH + h], et_);
  }
  rl4[e] = rv; tl4[e] = tv;
}

// ---------------- K4: CSR fill + per-edge mix coefficients (in-place over rl/tl) ----------------
__global__ void k_fillcoef(const int* __restrict__ ei, const float* __restrict__ elen,
                           const int* __restrict__ start, int* __restrict__ cursor, int* __restrict__ csr,
                           float4* __restrict__ rl4, float4* __restrict__ tl4,
                           const float4* __restrict__ rsum4, const float4* __restrict__ tsum4,
                           const float* __restrict__ mixb, const float* __restrict__ mixs, int E, int N) {
  int e = blockIdx.x * blockDim.x + threadIdx.x;
  if (e >= E) return;
  int r = ei[E + e];
  float len = elen[e];
  int pos = atomicAdd(&cursor[r], 1);
  csr[start[r] + pos] = e;
  float4 rv = rl4[e], tv = tl4[e];
  float4 rs = rsum4[r], ts = tsum4[r];
  float* rvp = (float*)&rv; float* tvp = (float*)&tv;
  const float* rsp = (const float*)&rs; const float* tsp = (const float*)&ts;
  float c1v[NH], c2v[NH];
  #pragma unroll
  for (int h = 0; h < NH; ++h) {
    float ar = rvp[h] / (rsp[h] + 1e-9f);
    float at = tvp[h] / (tsp[h] + 1e-9f);
    float g = sigmoidf_(mixb[h] + mixs[h] * len);
    float ba = g * ar + (1.f - g) * at;
    c1v[h] = ba * g;
    c2v[h] = ba * (1.f - g);
  }
  rl4[e] = make_float4(c1v[0], c1v[1], c1v[2], c1v[3]);
  tl4[e] = make_float4(c2v[0], c2v[1], c2v[2], c2v[3]);
}

// ---------------- K5: gather-aggregate per receiver + correction + @Wout + residual ----------------
__global__ __launch_bounds__(256)
void k_aggout(const int* __restrict__ ei, const int* __restrict__ start, const int* __restrict__ csr,
              const float4* __restrict__ c1v4, const float4* __restrict__ c2v4,
              const float* __restrict__ pt, const float* __restrict__ x,
              const float* __restrict__ Wout, float* __restrict__ out, int N) {
  __shared__ float wout_s[NF * NF];
  __shared__ float am_s[4][NF];
  int tid = threadIdx.x;
  {
    const float4* w4 = (const float4*)Wout;
    float4* s4 = (float4*)wout_s;
    for (int i = tid; i < NF * NF / 4; i += 256) s4[i] = w4[i];
  }
  int w = tid >> 6, g = tid & 63;
  int n = blockIdx.x * 4 + w;
  float acc = 0.f;
  float sc1[NH] = {0.f, 0.f, 0.f, 0.f}, sc2[NH] = {0.f, 0.f, 0.f, 0.f};
  if (n < N) {
    int i0 = start[n], i1 = start[n + 1];
    for (int i = i0; i < i1; ++i) {
      int e = csr[i];
      int s = ei[e];
      float4 a = c1v4[e], b = c2v4[e];
      const float* ap = (const float*)&a; const float* bp = (const float*)&b;
      const float* base = pt + (size_t)s * (2 * NH * NF) + g;
      #pragma unroll
      for (int h = 0; h < NH; ++h) {
        acc += ap[h] * base[h * NF] + bp[h] * base[(NH + h) * NF];
        sc1[h] += ap[h]; sc2[h] += bp[h];
      }
    }
    const float* baseN = pt + (size_t)n * (2 * NH * NF) + g;
    #pragma unroll
    for (int h = 0; h < NH; ++h)
      acc -= sc1[h] * baseN[h * NF] + sc2[h] * baseN[(NH + h) * NF];
    acc *= (1.f / NH);
  }
  am_s[w][g] = acc;
  __syncthreads();
  if (n < N) {
    float o = x[(size_t)n * NF + g];
    #pragma unroll 8
    for (int f = 0; f < NF; ++f) o += am_s[w][f] * wout_s[f * NF + g];
    out[(size_t)n * NF + g] = o;
  }
}

extern "C" void kernel_launch(void* const* d_in, const int* in_sizes, int n_in,
                              void* d_out, int out_size, void* d_ws, size_t ws_size,
                              hipStream_t stream) {
  const float* x    = (const float*)d_in[0];
  const int*   ei   = (const int*)d_in[1];
  // d_in[2] = edge_vec, unused by the reference
  const float* elen = (const float*)d_in[3];
  const float* Wp   = (const float*)d_in[4];
  const float* Wr   = (const float*)d_in[5];
  const float* Wt   = (const float*)d_in[6];
  const float* rsc  = (const float*)d_in[7];
  const float* tsc  = (const float*)d_in[8];
  const float* rdls = (const float*)d_in[9];
  const float* rtb  = (const float*)d_in[10];
  const float* rtw  = (const float*)d_in[11];
  const float* mixb = (const float*)d_in[12];
  const float* mixs = (const float*)d_in[13];
  const float* dW1  = (const float*)d_in[14];
  const float* db1  = (const float*)d_in[15];
  const float* dw2  = (const float*)d_in[16];
  const float* db2  = (const float*)d_in[17];
  const float* tW1  = (const float*)d_in[18];
  const float* tb1  = (const float*)d_in[19];
  const float* tw2  = (const float*)d_in[20];
  const float* tb2  = (const float*)d_in[21];
  const float* Wout = (const float*)d_in[22];

  int N = in_sizes[0] / NF;
  int E = in_sizes[3];

  float* p = (float*)d_ws;
  float* pt   = p; p += (size_t)N * 2 * NH * NF;  // [n][8][64]
  float* sr   = p; p += (size_t)N * NH;
  float* st   = p; p += (size_t)N * NH;
  float* doff = p; p += (size_t)N * NH;
  float* toff = p; p += (size_t)N * NH;
  float* rl   = p; p += (size_t)E * NH;           // logits -> exp -> c1
  float* tl   = p; p += (size_t)E * NH;           // logits -> exp -> c2
  float* rsum = p; p += (size_t)N * NH;
  float* tsum = p; p += (size_t)N * NH;
  unsigned* rmax = (unsigned*)p; p += (size_t)N * NH;
  unsigned* tmax = (unsigned*)p; p += (size_t)N * NH;
  int* deg    = (int*)p; p += N;
  int* cursor = (int*)p; p += N;
  int* startp = (int*)p; p += N + 1;
  int* csr    = (int*)p; p += E;

  // K0: init
  k_init<<<(NH * N + 255) / 256, 256, 0, stream>>>(rsum, tsum, rmax, tmax, deg, cursor, N);
  // K1: tiled node pass
  {
    dim3 grid((N + NT - 1) / NT, 3);
    k_proj<<<grid, 256, 0, stream>>>(x, Wp, Wr, Wt, rsc, tsc, dW1, db1, dw2, db2,
                                     tW1, tb1, tw2, tb2, pt, sr, st, doff, toff, N);
  }
  // K2: logits + segment max + degree count
  k_logits<<<(E + 255) / 256, 256, 0, stream>>>(ei, elen, (const float4*)sr, (const float4*)st,
                                                (const float4*)doff, (const float4*)toff,
                                                rdls, rtb, rtw, (float4*)rl, (float4*)tl,
                                                rmax, tmax, deg, E, N);
  // K2b: scan degrees -> CSR starts
  k_scan<<<1, 1024, 0, stream>>>(deg, startp, N);
  // K3: exp + segment sum
  k_expsum<<<(E + 255) / 256, 256, 0, stream>>>(ei, (float4*)rl, (float4*)tl,
                                                (const uint4*)rmax, (const uint4*)tmax,
                                                rsum, tsum, E, N);
  // K4: CSR fill + coefficients
  k_fillcoef<<<(E + 255) / 256, 256, 0, stream>>>(ei, elen, startp, cursor, csr,
                                                  (float4*)rl, (float4*)tl,
                                                  (const float4*)rsum, (const float4*)tsum,
                                                  mixb, mixs, E, N);
  // K5: gather-aggregate + output
  k_aggout<<<(N + 3) / 4, 256, 0, stream>>>(ei, startp, csr, (const float4*)rl, (const float4*)tl,
                                            pt, x, Wout, (float*)d_out, N);
}

// Round 6
// 245.280 us; speedup vs baseline: 1.9830x; 1.5111x over previous
//
#include <hip/hip_runtime.h>
#include <math.h>

#define NH 4
#define NF 64
#define NM 32
#define NT 16  // nodes per block in k_proj

__device__ __forceinline__ float softplusf(float v){ return fmaxf(v, 0.f) + log1pf(expf(-fabsf(v))); }
__device__ __forceinline__ float sigmoidf_(float v){ return 1.f / (1.f + expf(-v)); }

// ---------------- K0: zero deg + cursor ----------------
__global__ void k_zero(int* __restrict__ z, int n) {
  int i = blockIdx.x * blockDim.x + threadIdx.x;
  if (i < n) z[i] = 0;
}

// ---------------- K0b: degree count ----------------
__global__ void k_count(const int* __restrict__ ei, int* __restrict__ deg, int E) {
  int e = blockIdx.x * blockDim.x + threadIdx.x;
  if (e < E) atomicAdd(&deg[ei[E + e]], 1);
}

// ---------------- K1: tiled node pass ----------------
// grid = (ceil(N/NT), 3); block = 256 = 4 heads x 64 cols.
// mat 0: ep (LDS) + sr/st + decay/temp MLPs (rdscale/rtb folded into doff/toff).
// mat 1/2: rp/tp -> pt[n][g][8], rows 0..3 = rp heads, 4..7 = tp heads.
__global__ void k_proj(const float* __restrict__ x,
                       const float* __restrict__ Wp, const float* __restrict__ Wr, const float* __restrict__ Wt,
                       const float* __restrict__ rsc, const float* __restrict__ tsc,
                       const float* __restrict__ dW1, const float* __restrict__ db1,
                       const float* __restrict__ dw2, const float* __restrict__ db2,
                       const float* __restrict__ tW1, const float* __restrict__ tb1,
                       const float* __restrict__ tw2, const float* __restrict__ tb2,
                       const float* __restrict__ rdls, const float* __restrict__ rtb,
                       float* __restrict__ pt,
                       float* __restrict__ sr, float* __restrict__ st,
                       float* __restrict__ doff, float* __restrict__ toff, int N) {
  int n0 = blockIdx.x * NT;
  int mat = blockIdx.y;
  int tid = threadIdx.x;
  int h = tid >> 6, g = tid & 63;
  __shared__ float xs[NT][NF];
  __shared__ float eps[NT][NH][NF];

  for (int i = tid; i < NT * NF; i += 256) {
    int n = i >> 6, f = i & 63;
    xs[n][f] = (n0 + n < N) ? x[(size_t)(n0 + n) * NF + f] : 0.f;
  }
  __syncthreads();

  const float* W = (mat == 0 ? Wp : (mat == 1 ? Wr : Wt)) + (size_t)h * NF * NF;
  float acc[NT];
  #pragma unroll
  for (int n = 0; n < NT; ++n) acc[n] = 0.f;
  #pragma unroll 4
  for (int f = 0; f < NF; ++f) {
    float wv = W[f * NF + g];
    #pragma unroll
    for (int n = 0; n < NT; ++n) acc[n] += xs[n][f] * wv;
  }

  if (mat != 0) {
    int row = (mat - 1) * NH + h;  // 0..7
    #pragma unroll
    for (int n = 0; n < NT; ++n)
      if (n0 + n < N) pt[(((size_t)(n0 + n)) * NF + g) * 8 + row] = acc[n];
    return;
  }

  // mat == 0: ep path
  #pragma unroll
  for (int n = 0; n < NT; ++n) eps[n][h][g] = acc[n];

  float rs = rsc[h * NF + g], ts = tsc[h * NF + g];
  for (int n = 0; n < NT; ++n) {
    float a = acc[n] * rs, b = acc[n] * ts;
    for (int off = 32; off; off >>= 1) { a += __shfl_xor(a, off); b += __shfl_xor(b, off); }
    if (g == 0 && n0 + n < N) { sr[(n0 + n) * NH + h] = a; st[(n0 + n) * NH + h] = b; }
  }
  __syncthreads();

  // MLPs: lanes 0..31 decay, 32..63 temp
  int m = g & 31;
  bool isTemp = (g >= 32);
  const float* W1 = isTemp ? tW1 : dW1;
  float bias = isTemp ? tb1[h * NM + m] : db1[h * NM + m];
  float w2v  = isTemp ? tw2[h * NM + m] : dw2[h * NM + m];
  float accm[NT];
  #pragma unroll
  for (int n = 0; n < NT; ++n) accm[n] = bias;
  #pragma unroll 4
  for (int f = 0; f < NF; ++f) {
    float wv = W1[(h * NF + f) * NM + m];
    #pragma unroll
    for (int n = 0; n < NT; ++n) accm[n] += eps[n][h][f] * wv;
  }
  for (int n = 0; n < NT; ++n) {
    float a = accm[n];
    float p = a * sigmoidf_(a) * w2v;  // silu * w2
    for (int off = 16; off; off >>= 1) p += __shfl_xor(p, off);
    if (m == 0 && n0 + n < N) {
      if (!isTemp) doff[(n0 + n) * NH + h] = p + db2[h] + softplusf(rdls[h]);
      else         toff[(n0 + n) * NH + h] = p + tb2[h] + rtb[h];
    }
  }
}

// ---------------- K2: exclusive prefix scan of degrees (single block) ----------------
__global__ void k_scan(const int* __restrict__ deg, int* __restrict__ start, int N) {
  __shared__ int sd[1024];
  __shared__ int sbase;
  int tid = threadIdx.x;
  if (tid == 0) sbase = 0;
  __syncthreads();
  int nc = (N + 1023) >> 10;
  for (int c = 0; c < nc; ++c) {
    int i = (c << 10) + tid;
    int v = (i < N) ? deg[i] : 0;
    sd[tid] = v;
    __syncthreads();
    for (int off = 1; off < 1024; off <<= 1) {
      int t = (tid >= off) ? sd[tid - off] : 0;
      __syncthreads();
      sd[tid] += t;
      __syncthreads();
    }
    int base = sbase;
    if (i < N) start[i] = base + sd[tid] - v;
    int total = sd[1023];
    __syncthreads();
    if (tid == 0) sbase = base + total;
    __syncthreads();
  }
  if (tid == 0) start[N] = sbase;
}

// ---------------- K3: per-edge logits + gate, written in CSR order ----------------
__global__ void k_edge(const int* __restrict__ ei, const float* __restrict__ elen,
                       const float4* __restrict__ sr4, const float4* __restrict__ st4,
                       const float4* __restrict__ doff4, const float4* __restrict__ toff4,
                       const float* __restrict__ rtw,
                       const float* __restrict__ mixb, const float* __restrict__ mixs,
                       const int* __restrict__ start, int* __restrict__ cursor,
                       float4* __restrict__ crl, float4* __restrict__ ctl, float4* __restrict__ cgv,
                       int* __restrict__ snd, int E) {
  int e = blockIdx.x * blockDim.x + threadIdx.x;
  if (e >= E) return;
  int s = ei[e], r = ei[E + e];
  float len = elen[e];
  int slot = start[r] + atomicAdd(&cursor[r], 1);
  float4 a = sr4[s], b = sr4[r], c = st4[s], d = st4[r], dof = doff4[r], tof = toff4[r];
  const float* ap = (const float*)&a; const float* bp = (const float*)&b;
  const float* cp = (const float*)&c; const float* dp = (const float*)&d;
  const float* dofp = (const float*)&dof; const float* tofp = (const float*)&tof;
  float rlv[NH], tlv[NH], gv[NH];
  #pragma unroll
  for (int h = 0; h < NH; ++h) {
    float temp = softplusf(tofp[h] + rtw[h] * len);
    rlv[h] = (ap[h] - bp[h] - dofp[h] * len) / (temp + 1e-4f);
    tlv[h] = cp[h] - dp[h];
    gv[h] = sigmoidf_(mixb[h] + mixs[h] * len);
  }
  crl[slot] = make_float4(rlv[0], rlv[1], rlv[2], rlv[3]);
  ctl[slot] = make_float4(tlv[0], tlv[1], tlv[2], tlv[3]);
  cgv[slot] = make_float4(gv[0], gv[1], gv[2], gv[3]);
  snd[slot] = s;
}

// ---------------- K4: per-receiver softmax + gather-aggregate + Wout + residual ----------------
__global__ __launch_bounds__(256)
void k_aggout(const int* __restrict__ start, const int* __restrict__ snd,
              const float4* __restrict__ crl, const float4* __restrict__ ctl, const float4* __restrict__ cgv,
              const float* __restrict__ pt, const float* __restrict__ x,
              const float* __restrict__ Wout, float* __restrict__ out, int N) {
  __shared__ float wout_s[NF * NF];
  __shared__ float coef_s[4][64][8];
  __shared__ int   snd_s[4][64];
  __shared__ float am_s[4][NF];
  int tid = threadIdx.x;
  {
    const float4* w4 = (const float4*)Wout;
    float4* s4 = (float4*)wout_s;
    for (int i = tid; i < NF * NF / 4; i += 256) s4[i] = w4[i];
  }
  __syncthreads();   // only block-wide barrier; everything after is wave-local
  int w = tid >> 6, g = tid & 63;
  int n = blockIdx.x * 4 + w;
  if (n >= N) return;
  int i0 = start[n], i1 = start[n + 1];

  // pass A: per-head max (edge-parallel, lane = edge)
  float rm[NH] = {-1e30f, -1e30f, -1e30f, -1e30f};
  float tm[NH] = {-1e30f, -1e30f, -1e30f, -1e30f};
  for (int i = i0 + g; i < i1; i += 64) {
    float4 rv = crl[i], tv = ctl[i];
    const float* rp_ = (const float*)&rv; const float* tp_ = (const float*)&tv;
    #pragma unroll
    for (int h = 0; h < NH; ++h) { rm[h] = fmaxf(rm[h], rp_[h]); tm[h] = fmaxf(tm[h], tp_[h]); }
  }
  #pragma unroll
  for (int off = 32; off; off >>= 1)
    #pragma unroll
    for (int h = 0; h < NH; ++h) {
      rm[h] = fmaxf(rm[h], __shfl_xor(rm[h], off));
      tm[h] = fmaxf(tm[h], __shfl_xor(tm[h], off));
    }

  // pass B: per-head exp-sum
  float rs_[NH] = {0.f, 0.f, 0.f, 0.f}, ts_[NH] = {0.f, 0.f, 0.f, 0.f};
  for (int i = i0 + g; i < i1; i += 64) {
    float4 rv = crl[i], tv = ctl[i];
    const float* rp_ = (const float*)&rv; const float* tp_ = (const float*)&tv;
    #pragma unroll
    for (int h = 0; h < NH; ++h) { rs_[h] += expf(rp_[h] - rm[h]); ts_[h] += expf(tp_[h] - tm[h]); }
  }
  #pragma unroll
  for (int off = 32; off; off >>= 1)
    #pragma unroll
    for (int h = 0; h < NH; ++h) { rs_[h] += __shfl_xor(rs_[h], off); ts_[h] += __shfl_xor(ts_[h], off); }
  #pragma unroll
  for (int h = 0; h < NH; ++h) { rs_[h] = 1.f / (rs_[h] + 1e-9f); ts_[h] = 1.f / (ts_[h] + 1e-9f); }

  // pass C: coefficients (lane=edge) + gather-aggregate (lane=feature)
  float acc = 0.f;
  float sc1[NH] = {0.f, 0.f, 0.f, 0.f}, sc2[NH] = {0.f, 0.f, 0.f, 0.f};
  for (int base = i0; base < i1; base += 64) {
    int i = base + g;
    if (i < i1) {
      float4 rv = crl[i], tv = ctl[i], gv = cgv[i];
      const float* rp_ = (const float*)&rv; const float* tp_ = (const float*)&tv;
      const float* gp_ = (const float*)&gv;
      #pragma unroll
      for (int h = 0; h < NH; ++h) {
        float ar = expf(rp_[h] - rm[h]) * rs_[h];
        float at = expf(tp_[h] - tm[h]) * ts_[h];
        float gg = gp_[h];
        float ba = gg * ar + (1.f - gg) * at;
        float c1 = ba * gg, c2 = ba * (1.f - gg);
        coef_s[w][g][h] = c1; coef_s[w][g][4 + h] = c2;
        sc1[h] += c1; sc2[h] += c2;
      }
      snd_s[w][g] = snd[i];
    }
    int cnt = min(64, i1 - base);
    for (int j = 0; j < cnt; ++j) {
      int s = snd_s[w][j];
      const float4* b4 = (const float4*)(pt + ((size_t)s * NF + g) * 8);
      float4 rpv = b4[0], tpv = b4[1];
      const float* rpp = (const float*)&rpv; const float* tpp = (const float*)&tpv;
      #pragma unroll
      for (int h = 0; h < NH; ++h)
        acc += coef_s[w][j][h] * rpp[h] + coef_s[w][j][4 + h] * tpp[h];
    }
  }
  // reduce coefficient sums across the wave (each lane held its own edges' share)
  #pragma unroll
  for (int off = 32; off; off >>= 1)
    #pragma unroll
    for (int h = 0; h < NH; ++h) { sc1[h] += __shfl_xor(sc1[h], off); sc2[h] += __shfl_xor(sc2[h], off); }

  const float4* bn4 = (const float4*)(pt + ((size_t)n * NF + g) * 8);
  float4 rpn = bn4[0], tpn = bn4[1];
  const float* rnp = (const float*)&rpn; const float* tnp = (const float*)&tpn;
  #pragma unroll
  for (int h = 0; h < NH; ++h) acc -= sc1[h] * rnp[h] + sc2[h] * tnp[h];
  acc *= (1.f / NH);

  am_s[w][g] = acc;   // wave-local LDS; no block barrier needed
  float o = x[(size_t)n * NF + g];
  #pragma unroll 8
  for (int f = 0; f < NF; ++f) o += am_s[w][f] * wout_s[f * NF + g];
  out[(size_t)n * NF + g] = o;
}

extern "C" void kernel_launch(void* const* d_in, const int* in_sizes, int n_in,
                              void* d_out, int out_size, void* d_ws, size_t ws_size,
                              hipStream_t stream) {
  const float* x    = (const float*)d_in[0];
  const int*   ei   = (const int*)d_in[1];
  // d_in[2] = edge_vec, unused by the reference
  const float* elen = (const float*)d_in[3];
  const float* Wp   = (const float*)d_in[4];
  const float* Wr   = (const float*)d_in[5];
  const float* Wt   = (const float*)d_in[6];
  const float* rsc  = (const float*)d_in[7];
  const float* tsc  = (const float*)d_in[8];
  const float* rdls = (const float*)d_in[9];
  const float* rtb  = (const float*)d_in[10];
  const float* rtw  = (const float*)d_in[11];
  const float* mixb = (const float*)d_in[12];
  const float* mixs = (const float*)d_in[13];
  const float* dW1  = (const float*)d_in[14];
  const float* db1  = (const float*)d_in[15];
  const float* dw2  = (const float*)d_in[16];
  const float* db2  = (const float*)d_in[17];
  const float* tW1  = (const float*)d_in[18];
  const float* tb1  = (const float*)d_in[19];
  const float* tw2  = (const float*)d_in[20];
  const float* tb2  = (const float*)d_in[21];
  const float* Wout = (const float*)d_in[22];

  int N = in_sizes[0] / NF;
  int E = in_sizes[3];

  float* p = (float*)d_ws;
  float* pt   = p; p += (size_t)N * NF * 8;   // [n][g][8]
  float* sr   = p; p += (size_t)N * NH;
  float* st   = p; p += (size_t)N * NH;
  float* doff = p; p += (size_t)N * NH;
  float* toff = p; p += (size_t)N * NH;
  float* crl  = p; p += (size_t)E * NH;       // CSR-ordered radial logits
  float* ctl  = p; p += (size_t)E * NH;       // CSR-ordered tangential logits
  float* cgv  = p; p += (size_t)E * NH;       // CSR-ordered mix gate
  int* snd    = (int*)p; p += E;              // CSR-ordered sender ids
  int* deg    = (int*)p; p += N;
  int* cursor = (int*)p; p += N;
  int* startp = (int*)p; p += N + 1;

  // K0: zero deg + cursor (contiguous)
  k_zero<<<(2 * N + 255) / 256, 256, 0, stream>>>(deg, 2 * N);
  // K0b: degree count
  k_count<<<(E + 255) / 256, 256, 0, stream>>>(ei, deg, E);
  // K1: tiled node pass
  {
    dim3 grid((N + NT - 1) / NT, 3);
    k_proj<<<grid, 256, 0, stream>>>(x, Wp, Wr, Wt, rsc, tsc, dW1, db1, dw2, db2,
                                     tW1, tb1, tw2, tb2, rdls, rtb,
                                     pt, sr, st, doff, toff, N);
  }
  // K2: scan degrees -> CSR starts
  k_scan<<<1, 1024, 0, stream>>>(deg, startp, N);
  // K3: per-edge logits into CSR slots
  k_edge<<<(E + 255) / 256, 256, 0, stream>>>(ei, elen, (const float4*)sr, (const float4*)st,
                                              (const float4*)doff, (const float4*)toff,
                                              rtw, mixb, mixs, startp, cursor,
                                              (float4*)crl, (float4*)ctl, (float4*)cgv, snd, E);
  // K4: softmax + aggregate + output
  k_aggout<<<(N + 3) / 4, 256, 0, stream>>>(startp, snd, (const float4*)crl, (const float4*)ctl,
                                            (const float4*)cgv, pt, x, Wout, (float*)d_out, N);
}